// Round 1
// 256.099 us; speedup vs baseline: 1.0211x; 1.0211x over previous
//
#include <hip/hip_runtime.h>

// MAB block, MFMA bf16, round 7: de-scratch the attention K-loop.
// The r6 kernel passed its double-buffer arrays (short8 ka[4]/va[4]/kb[4]/vb[4])
// as pointers into lambdas -> SROA failed -> arrays demoted to scratch
// (VGPR_Count=56, ~9.5k cycles/tile from L2-resident scratch round-trips).
// r7 rewrites the loop with named scalar registers + macros, single-buffers V
// (loaded at body start, consumed ~400cy later) to fit the 128-VGPR cap at
// 4 waves/EU. Everything else unchanged.

typedef float fx4 __attribute__((ext_vector_type(4)));
typedef short short8 __attribute__((ext_vector_type(8)));
typedef short shortx4 __attribute__((ext_vector_type(4)));
typedef unsigned int uint2v __attribute__((ext_vector_type(2)));

#define BB  4
#define NN  2048
#define DD  256
#define HH  4
#define DHH 64

__device__ __forceinline__ float bf2f(unsigned short u) {
    union { unsigned int i; float f; } v; v.i = ((unsigned int)u) << 16; return v.f;
}
__device__ __forceinline__ unsigned short f2bf(float f) {
    union { float f; unsigned int i; } v; v.f = f;
    unsigned int r = v.i + 0x7FFF + ((v.i >> 16) & 1);   // RNE
    return (unsigned short)(r >> 16);
}
__device__ __forceinline__ unsigned int fbits(float f) {
    union { float f; unsigned int i; } v; v.f = f; return v.i;
}
__device__ __forceinline__ unsigned int packbf(float lo, float hi) {
    unsigned int a = fbits(lo), b = fbits(hi);
    a = (a + 0x7FFF + ((a >> 16) & 1)) >> 16;
    b = (b + 0x7FFF + ((b >> 16) & 1)) & 0xFFFF0000u;
    return a | b;
}

// ---------------------------------------------------------------------------
// Weight prep: WT[n][k] = bf16(W[k][n]) for the 5 weight matrices (256x256).
// ---------------------------------------------------------------------------
__global__ __launch_bounds__(256) void wt_prep(
        const float* __restrict__ w0, const float* __restrict__ w1,
        const float* __restrict__ w2, const float* __restrict__ w3,
        const float* __restrict__ w4, unsigned short* __restrict__ dst) {
    __shared__ unsigned short T[64 * 73];
    const int tid = threadIdx.x;
    const int z = blockIdx.z;
    const float* W = (z == 0) ? w0 : (z == 1) ? w1 : (z == 2) ? w2 : (z == 3) ? w3 : w4;
    unsigned short* WT = dst + z * 65536;
    const int nb = blockIdx.x * 64, kb = blockIdx.y * 64;
    {
        int kl = tid >> 2, c0 = (tid & 3) * 16;
        const float* src = W + (size_t)(kb + kl) * DD + nb + c0;
#pragma unroll
        for (int i = 0; i < 16; ++i) T[kl * 73 + c0 + i] = f2bf(src[i]);
    }
    __syncthreads();
    {
        int nl = tid >> 2, k0 = (tid & 3) * 16;
        short8 o0, o1;
#pragma unroll
        for (int i = 0; i < 8; ++i) {
            o0[i] = (short)T[(k0 + i) * 73 + nl];
            o1[i] = (short)T[(k0 + 8 + i) * 73 + nl];
        }
        short8* d = (short8*)(WT + (size_t)(nb + nl) * DD + kb + k0);
        d[0] = o0; d[1] = o1;
    }
}

// ---------------------------------------------------------------------------
// V transpose: VT[(b*4+h)*64 + d][key] = Vp[b*2048+key][h*64+d]. grid(128,4).
// ---------------------------------------------------------------------------
__global__ __launch_bounds__(256) void vt_prep(
        const unsigned short* __restrict__ Vp, unsigned short* __restrict__ VT) {
    __shared__ unsigned short T[64 * 73];
    const int tid = threadIdx.x;
    const int hb = blockIdx.y;
    const int b = blockIdx.x >> 5;
    const int keyb = (blockIdx.x & 31) * 64;
    {
        int kl = tid >> 2, c0 = (tid & 3) * 16;
        const short8* src = (const short8*)(Vp + (size_t)(b * NN + keyb + kl) * DD + hb * DHH + c0);
        short8 v0 = src[0], v1 = src[1];
#pragma unroll
        for (int i = 0; i < 8; ++i) {
            T[kl * 73 + c0 + i]     = (unsigned short)v0[i];
            T[kl * 73 + c0 + 8 + i] = (unsigned short)v1[i];
        }
    }
    __syncthreads();
    {
        int dl = tid >> 2, k0 = (tid & 3) * 16;
        short8 o0, o1;
#pragma unroll
        for (int i = 0; i < 8; ++i) {
            o0[i] = (short)T[(k0 + i) * 73 + dl];
            o1[i] = (short)T[(k0 + 8 + i) * 73 + dl];
        }
        short8* d = (short8*)(VT + (size_t)((b * HH + hb) * DHH + dl) * NN + keyb + k0);
        d[0] = o0; d[1] = o1;
    }
}

// ---------------------------------------------------------------------------
// 32-row GEMM body: C[r0..r0+32, c-half] = A @ W + bias. 4 waves, wave =
// 32 rows x 32 cols. W-frags hoisted. AIN: 0 fp32 A, 1 bf16 A.
// EP: 0 bias->bf16, 1 relu->bf16.
// ---------------------------------------------------------------------------
template<int AIN, int EP>
__device__ __forceinline__ void gemm32_body(
        const void* __restrict__ Ain, const unsigned short* __restrict__ WT,
        const float* __restrict__ bias, void* __restrict__ Cout, int bx) {
    __shared__ unsigned short As[32 * 264];
    const int tid = threadIdx.x;
    const int lane = tid & 63, w = tid >> 6;
    const int l15 = lane & 15, quad = lane >> 4;
    const int r0 = (bx >> 1) * 32;
    const int c0w = (bx & 1) * 128 + w * 32;
    short8 wf[8][2];
#pragma unroll
    for (int kc = 0; kc < 8; ++kc)
#pragma unroll
        for (int dt = 0; dt < 2; ++dt)
            wf[kc][dt] = *(const short8*)(WT + (size_t)(c0w + dt * 16 + l15) * DD + kc * 32 + 8 * quad);
    float bv[2];
#pragma unroll
    for (int dt = 0; dt < 2; ++dt) bv[dt] = bias[c0w + dt * 16 + l15];
    {   // stage A tile (32 x 256) as bf16; thread: 32 elems
        int row = tid >> 3, c0 = (tid & 7) * 32;
        short8 o[4];
        if (AIN == 0) {
            const fx4* s4 = (const fx4*)((const float*)Ain + (size_t)(r0 + row) * DD + c0);
#pragma unroll
            for (int j = 0; j < 4; ++j) {
                fx4 v0 = s4[2 * j], v1 = s4[2 * j + 1];
#pragma unroll
                for (int i = 0; i < 4; ++i) {
                    o[j][i]     = (short)f2bf(v0[i]);
                    o[j][i + 4] = (short)f2bf(v1[i]);
                }
            }
        } else {
            const short8* s8 = (const short8*)((const unsigned short*)Ain + (size_t)(r0 + row) * DD + c0);
#pragma unroll
            for (int j = 0; j < 4; ++j) o[j] = s8[j];
        }
        short8* d = (short8*)(As + row * 264 + c0);
#pragma unroll
        for (int j = 0; j < 4; ++j) d[j] = o[j];
    }
    __syncthreads();
    fx4 acc[2][2];
#pragma unroll
    for (int mt = 0; mt < 2; ++mt)
#pragma unroll
        for (int dt = 0; dt < 2; ++dt) acc[mt][dt] = (fx4){0.f, 0.f, 0.f, 0.f};
#pragma unroll
    for (int kc = 0; kc < 8; ++kc) {
        short8 a0 = *(const short8*)(As + l15 * 264 + kc * 32 + 8 * quad);
        short8 a1 = *(const short8*)(As + (16 + l15) * 264 + kc * 32 + 8 * quad);
#pragma unroll
        for (int dt = 0; dt < 2; ++dt) {
            acc[0][dt] = __builtin_amdgcn_mfma_f32_16x16x32_bf16(a0, wf[kc][dt], acc[0][dt], 0, 0, 0);
            acc[1][dt] = __builtin_amdgcn_mfma_f32_16x16x32_bf16(a1, wf[kc][dt], acc[1][dt], 0, 0, 0);
        }
    }
#pragma unroll
    for (int mt = 0; mt < 2; ++mt)
#pragma unroll
        for (int r = 0; r < 4; ++r) {
            const size_t grow = r0 + mt * 16 + 4 * quad + r;
#pragma unroll
            for (int dt = 0; dt < 2; ++dt) {
                float v = acc[mt][dt][r] + bv[dt];
                if (EP == 1) v = fmaxf(v, 0.0f);
                ((unsigned short*)Cout)[grow * DD + c0w + dt * 16 + l15] = f2bf(v);
            }
        }
}

// Fused QKV projections: grid (512, 3); y selects {Q->Qp, K->Kp, K->Vp}.
__global__ __launch_bounds__(256, 4) void qkv_mfma(
        const float* __restrict__ Q, const float* __restrict__ K,
        const unsigned short* __restrict__ WT5,
        const float* __restrict__ bq, const float* __restrict__ bk,
        const float* __restrict__ bv,
        unsigned short* __restrict__ Qp, unsigned short* __restrict__ Kp,
        unsigned short* __restrict__ Vp) {
    const int z = blockIdx.y;
    const float* A = (z == 0) ? Q : K;
    const float* bias = (z == 0) ? bq : (z == 1) ? bk : bv;
    unsigned short* C = (z == 0) ? Qp : (z == 1) ? Kp : Vp;
    gemm32_body<0, 0>(A, WT5 + z * 65536, bias, C, blockIdx.x);
}

// FFN1: H1 = relu(O @ W1 + b1), O fp32.
__global__ __launch_bounds__(256, 4) void ffn1_mfma(
        const float* __restrict__ O, const unsigned short* __restrict__ WT1,
        const float* __restrict__ b1, unsigned short* __restrict__ H1) {
    gemm32_body<0, 1>(O, WT1, b1, H1, blockIdx.x);
}

// ---------------------------------------------------------------------------
// FFN2 + residual + LayerNorm fused: out = LN(R + A@W2 + b2), fp32 out.
// Block = 16 rows x 256 cols, 8 waves (wave = 16x32), W-frags hoisted.
// ---------------------------------------------------------------------------
__global__ __launch_bounds__(512, 4) void gemm_ffn2_ln(
        const unsigned short* __restrict__ Ain, const unsigned short* __restrict__ WT,
        const float* __restrict__ bias, const float* __restrict__ R,
        const float* __restrict__ g, const float* __restrict__ be,
        float* __restrict__ out) {
    __shared__ unsigned short As[16 * 264];
    __shared__ float lnb[2][8][16];
    const int tid = threadIdx.x;
    const int lane = tid & 63, w = tid >> 6;          // w in 0..7
    const int l15 = lane & 15, quad = lane >> 4;
    const int r0 = blockIdx.x * 16;
    const int c0w = w * 32;
    short8 wf[8][2];
#pragma unroll
    for (int kc = 0; kc < 8; ++kc)
#pragma unroll
        for (int dt = 0; dt < 2; ++dt)
            wf[kc][dt] = *(const short8*)(WT + (size_t)(c0w + dt * 16 + l15) * DD + kc * 32 + 8 * quad);
    float bv[2], gv[2], ev[2];
#pragma unroll
    for (int dt = 0; dt < 2; ++dt) {
        int col = c0w + dt * 16 + l15;
        bv[dt] = bias[col]; gv[dt] = g[col]; ev[dt] = be[col];
    }
    {   // stage A: 512 threads x 16B
        int row = tid >> 5, c0 = (tid & 31) * 8;
        *(short8*)(As + row * 264 + c0) = *(const short8*)(Ain + (size_t)(r0 + row) * DD + c0);
    }
    __syncthreads();
    fx4 acc[2];
#pragma unroll
    for (int i = 0; i < 2; ++i) acc[i] = (fx4){0.f, 0.f, 0.f, 0.f};
#pragma unroll
    for (int kc = 0; kc < 8; ++kc) {
        short8 a = *(const short8*)(As + l15 * 264 + kc * 32 + 8 * quad);
#pragma unroll
        for (int dt = 0; dt < 2; ++dt)
            acc[dt] = __builtin_amdgcn_mfma_f32_16x16x32_bf16(a, wf[kc][dt], acc[dt], 0, 0, 0);
    }
    float v[4][2], p1[4], p2[4];
#pragma unroll
    for (int r = 0; r < 4; ++r) {
        p1[r] = 0.f; p2[r] = 0.f;
        const size_t grow = r0 + 4 * quad + r;
#pragma unroll
        for (int dt = 0; dt < 2; ++dt) {
            float x = acc[dt][r] + bv[dt] + R[grow * DD + c0w + dt * 16 + l15];
            v[r][dt] = x; p1[r] += x; p2[r] += x * x;
        }
    }
#pragma unroll
    for (int r = 0; r < 4; ++r) {
#pragma unroll
        for (int off = 1; off <= 8; off <<= 1) {
            p1[r] += __shfl_xor(p1[r], off);
            p2[r] += __shfl_xor(p2[r], off);
        }
    }
    if (l15 == 0) {
#pragma unroll
        for (int r = 0; r < 4; ++r) {
            lnb[0][w][4 * quad + r] = p1[r];
            lnb[1][w][4 * quad + r] = p2[r];
        }
    }
    __syncthreads();
#pragma unroll
    for (int r = 0; r < 4; ++r) {
        const int row = 4 * quad + r;
        float s1 = 0.f, s2 = 0.f;
#pragma unroll
        for (int ww = 0; ww < 8; ++ww) { s1 += lnb[0][ww][row]; s2 += lnb[1][ww][row]; }
        float mean = s1 * (1.0f / 256.0f);
        float var  = s2 * (1.0f / 256.0f) - mean * mean;
        float rstd = rsqrtf(var + 1e-5f);
        const size_t grow = r0 + row;
#pragma unroll
        for (int dt = 0; dt < 2; ++dt)
            out[grow * DD + c0w + dt * 16 + l15] = (v[r][dt] - mean) * rstd * gv[dt] + ev[dt];
    }
}

// ---------------------------------------------------------------------------
// Flash attention, O^T form, no-max softmax (|s| <= ~2 by construction).
// Block = 32 q-rows, 4 waves: wave w -> q-subtile (w&1), K-half (w>>1).
// Per 32-key tile: S^T = K.Q^T (C col = q = l15) -> p = exp(s/8) per-thread
// -> pack -> XOR-swizzled LDS exchange -> od^T += V^T.P^T (od col = q).
// r7: all loop state in NAMED scalar registers (no arrays / lambda pointers
// -> no scratch demotion). K double-buffered (ka*/kb*); V single-buffered,
// issued at body start (covered by QK+exp+pack+LDS-exchange latency), issued
// BEFORE next-tile K so the V vmcnt wait leaves the K prefetch in flight.
// ---------------------------------------------------------------------------
__global__ __launch_bounds__(256, 4) void attn_mfma(
        const unsigned short* __restrict__ Qp, const unsigned short* __restrict__ Kp,
        const unsigned short* __restrict__ VT, float* __restrict__ Opre) {
    __shared__ unsigned int pbuf[4][256];     // per-wave P exchange, pitch 16 dw
    __shared__ float macc[2][16][68];         // kh0 partial O^T [qs][q][d]
    __shared__ float lbuf[32];                // kh0 partial l    [qs*16+q]
    const int tid = threadIdx.x;
    const int lane = tid & 63, w = tid >> 6;
    const int l15 = lane & 15, quad = lane >> 4;
    const int qs = w & 1, kh = w >> 1;
    const int gb = blockIdx.x;
    const int bh = ((gb & 7) << 1) | ((gb >> 9) & 1);   // XCD-locality swizzle
    const int qc = (gb >> 3) & 63;
    const int h  = bh & 3;
    const int b  = bh >> 2;
    const int qrow = qc * 32 + qs * 16;
    const int sw = 4 * ((l15 >> 1) & 3);                // bank swizzle (per l15)

    short8 aq0, aq1;
    {
        const unsigned short* qptr = Qp + ((size_t)(b * NN + qrow + l15) * DD + h * DHH + 8 * quad);
        aq0 = *(const short8*)qptr;
        aq1 = *(const short8*)(qptr + 32);
    }
    fx4 od0 = (fx4){0.f, 0.f, 0.f, 0.f};
    fx4 od1 = (fx4){0.f, 0.f, 0.f, 0.f};
    fx4 od2 = (fx4){0.f, 0.f, 0.f, 0.f};
    fx4 od3 = (fx4){0.f, 0.f, 0.f, 0.f};
    float lsum = 0.0f;

    unsigned int* pw = &pbuf[w][0];
    const int wcol = (2 * quad) ^ sw;         // write cols (pairs t=2q,2q+1 / +8)
    const int rcol = (4 * quad) ^ sw;         // read col group (t=4Q..4Q+3)
    const unsigned short* kbase = Kp + ((size_t)(b * NN) * DD + h * DHH + 8 * quad);
    const unsigned short* vbase = VT + ((size_t)((b * HH + h) * DHH)) * NN + 8 * quad;

    // loop state: named registers only (the whole point of r7)
    short8 ka0, ka1, ka2, ka3;     // K frags, buffer A
    short8 kb0, kb1, kb2, kb3;     // K frags, buffer B
    short8 v0, v1, v2, v3;         // V frags, current tile

#define PREF_K(K0, K1, K2, K3, T) do {                                        \
        const int kt_ = kh * 1024 + (T) * 32;                                 \
        const unsigned short* kp0_ = kbase + (size_t)(kt_ + l15) * DD;        \
        const unsigned short* kp1_ = kbase + (size_t)(kt_ + 16 + l15) * DD;   \
        K0 = *(const short8*)kp0_;                                            \
        K1 = *(const short8*)(kp0_ + 32);                                     \
        K2 = *(const short8*)kp1_;                                            \
        K3 = *(const short8*)(kp1_ + 32);                                     \
    } while (0)

#define PREF_V(T) do {                                                        \
        const int kt_ = kh * 1024 + (T) * 32;                                 \
        v0 = *(const short8*)(vbase + (size_t)(l15) * NN + kt_);              \
        v1 = *(const short8*)(vbase + (size_t)(16 + l15) * NN + kt_);         \
        v2 = *(const short8*)(vbase + (size_t)(32 + l15) * NN + kt_);         \
        v3 = *(const short8*)(vbase + (size_t)(48 + l15) * NN + kt_);         \
    } while (0)

#define BODY(CK0, CK1, CK2, CK3, NK0, NK1, NK2, NK3, T) do {                  \
        PREF_V(T);                            /* V for THIS tile (used last) */\
        const int tn_ = ((T) + 1 < 32) ? (T) + 1 : 31;                        \
        PREF_K(NK0, NK1, NK2, NK3, tn_);      /* K for NEXT tile */           \
        const fx4 z_ = (fx4){0.f, 0.f, 0.f, 0.f};                             \
        fx4 s0_ = __builtin_amdgcn_mfma_f32_16x16x32_bf16(CK0, aq0, z_, 0, 0, 0); \
        s0_     = __builtin_amdgcn_mfma_f32_16x16x32_bf16(CK1, aq1, s0_, 0, 0, 0); \
        fx4 s1_ = __builtin_amdgcn_mfma_f32_16x16x32_bf16(CK2, aq0, z_, 0, 0, 0); \
        s1_     = __builtin_amdgcn_mfma_f32_16x16x32_bf16(CK3, aq1, s1_, 0, 0, 0); \
        s0_[0] = __expf(s0_[0] * 0.125f); s0_[1] = __expf(s0_[1] * 0.125f);   \
        s0_[2] = __expf(s0_[2] * 0.125f); s0_[3] = __expf(s0_[3] * 0.125f);   \
        s1_[0] = __expf(s1_[0] * 0.125f); s1_[1] = __expf(s1_[1] * 0.125f);   \
        s1_[2] = __expf(s1_[2] * 0.125f); s1_[3] = __expf(s1_[3] * 0.125f);   \
        lsum += s0_[0] + s0_[1] + s0_[2] + s0_[3];                            \
        lsum += s1_[0] + s1_[1] + s1_[2] + s1_[3];                            \
        uint2v w1_ = (uint2v){packbf(s0_[0], s0_[1]), packbf(s0_[2], s0_[3])};\
        uint2v w2_ = (uint2v){packbf(s1_[0], s1_[1]), packbf(s1_[2], s1_[3])};\
        *(uint2v*)(pw + l15 * 16 + wcol)       = w1_;   /* pairs t=2q,2q+1 */ \
        *(uint2v*)(pw + l15 * 16 + (wcol ^ 8)) = w2_;   /* pairs t=8+2q..  */ \
        short8 bp_ = *(const short8*)(pw + l15 * 16 + rcol); /* keys 8q..+7 */\
        od0 = __builtin_amdgcn_mfma_f32_16x16x32_bf16(v0, bp_, od0, 0, 0, 0); \
        od1 = __builtin_amdgcn_mfma_f32_16x16x32_bf16(v1, bp_, od1, 0, 0, 0); \
        od2 = __builtin_amdgcn_mfma_f32_16x16x32_bf16(v2, bp_, od2, 0, 0, 0); \
        od3 = __builtin_amdgcn_mfma_f32_16x16x32_bf16(v3, bp_, od3, 0, 0, 0); \
    } while (0)

    PREF_K(ka0, ka1, ka2, ka3, 0);
    for (int tt = 0; tt < 16; ++tt) {
        BODY(ka0, ka1, ka2, ka3, kb0, kb1, kb2, kb3, 2 * tt);
        BODY(kb0, kb1, kb2, kb3, ka0, ka1, ka2, ka3, 2 * tt + 1);
    }
#undef BODY
#undef PREF_V
#undef PREF_K

    // per-q total l for this wave (sum over quads)
    lsum += __shfl_xor(lsum, 16);
    lsum += __shfl_xor(lsum, 32);
    // ---- merge the two K-halves (plain adds; no max state) ----
    if (kh == 0) {
        *(fx4*)&macc[qs][l15][0 * 16 + 4 * quad] = od0;
        *(fx4*)&macc[qs][l15][1 * 16 + 4 * quad] = od1;
        *(fx4*)&macc[qs][l15][2 * 16 + 4 * quad] = od2;
        *(fx4*)&macc[qs][l15][3 * 16 + 4 * quad] = od3;
        if (quad == 0) lbuf[qs * 16 + l15] = lsum;
    }
    __syncthreads();
    if (kh == 1) {
        const float inv = 1.0f / (lsum + lbuf[qs * 16 + l15]);
        const size_t grow = (size_t)(b * NN) + qrow + l15;
        float* obase = Opre + grow * DD + h * DHH;
        const unsigned short* qpb = Qp + grow * DD + h * DHH;
#define OUT_DT(DT, OD) do {                                                   \
        fx4 mv_ = *(const fx4*)&macc[qs][l15][(DT) * 16 + 4 * quad];          \
        shortx4 rv_ = *(const shortx4*)(qpb + (DT) * 16 + 4 * quad);          \
        fx4 o_;                                                               \
        o_[0] = (OD[0] + mv_[0]) * inv + bf2f((unsigned short)rv_[0]);        \
        o_[1] = (OD[1] + mv_[1]) * inv + bf2f((unsigned short)rv_[1]);        \
        o_[2] = (OD[2] + mv_[2]) * inv + bf2f((unsigned short)rv_[2]);        \
        o_[3] = (OD[3] + mv_[3]) * inv + bf2f((unsigned short)rv_[3]);        \
        *(fx4*)(obase + (DT) * 16 + 4 * quad) = o_;                           \
    } while (0)
        OUT_DT(0, od0);
        OUT_DT(1, od1);
        OUT_DT(2, od2);
        OUT_DT(3, od3);
#undef OUT_DT
    }
}

// row LayerNorm: Y = LN(X)*g+be (fp32)
__global__ __launch_bounds__(64) void ln_rows(
        const float* __restrict__ X, const float* __restrict__ g,
        const float* __restrict__ be, float* __restrict__ Y) {
    const int lane = threadIdx.x;
    const size_t row = blockIdx.x;
    fx4 v = ((const fx4*)(X + row * DD))[lane];
    float s1 = v[0]+v[1]+v[2]+v[3];
    float s2 = v[0]*v[0]+v[1]*v[1]+v[2]*v[2]+v[3]*v[3];
#pragma unroll
    for (int off = 32; off >= 1; off >>= 1) {
        s1 += __shfl_xor(s1, off); s2 += __shfl_xor(s2, off);
    }
    float mean = s1 * (1.0f/256.0f);
    float var  = s2 * (1.0f/256.0f) - mean * mean;
    float rstd = rsqrtf(var + 1e-5f);
    fx4 gv = ((const fx4*)g)[lane];
    fx4 ev = ((const fx4*)be)[lane];
    fx4 o;
#pragma unroll
    for (int i = 0; i < 4; ++i) o[i] = (v[i]-mean)*rstd*gv[i] + ev[i];
    ((fx4*)(Y + row * DD))[lane] = o;
}

extern "C" void kernel_launch(void* const* d_in, const int* in_sizes, int n_in,
                              void* d_out, int out_size, void* d_ws, size_t ws_size,
                              hipStream_t stream) {
    (void)in_sizes; (void)n_in; (void)out_size; (void)ws_size;
    const float* Q     = (const float*)d_in[0];
    const float* K     = (const float*)d_in[1];
    const float* Wq    = (const float*)d_in[2];
    const float* bq    = (const float*)d_in[3];
    const float* Wk    = (const float*)d_in[4];
    const float* bk    = (const float*)d_in[5];
    const float* Wv    = (const float*)d_in[6];
    const float* bv    = (const float*)d_in[7];
    const float* W1    = (const float*)d_in[8];
    const float* b1    = (const float*)d_in[9];
    const float* W2    = (const float*)d_in[10];
    const float* b2    = (const float*)d_in[11];
    const float* g0    = (const float*)d_in[12];
    const float* beta0 = (const float*)d_in[13];
    const float* g1    = (const float*)d_in[14];
    const float* beta1 = (const float*)d_in[15];

    // Workspace: [0,4)Mi Qp bf16 (later H1 bf16); [4,8)Mi Kp; [8,12)Mi Vp;
    // [12,16)Mi VT; [16,24)Mi Opre f32; [24,32)Mi O f32; [32Mi,+640K) WT x5
    char* ws = (char*)d_ws;
    unsigned short* Qp  = (unsigned short*)(ws);
    unsigned short* Kp  = (unsigned short*)(ws + (4u  << 20));
    unsigned short* Vp  = (unsigned short*)(ws + (8u  << 20));
    unsigned short* VT  = (unsigned short*)(ws + (12u << 20));
    float*          Opre= (float*)(ws + (16u << 20));
    float*          O   = (float*)(ws + (24u << 20));
    unsigned short* WT5 = (unsigned short*)(ws + (32u << 20));
    unsigned short* H1  = Qp;
    float*          out = (float*)d_out;

    const unsigned short* WT1 = WT5 + 3 * 65536;
    const unsigned short* WT2 = WT5 + 4 * 65536;

    const int M = BB * NN;                        // 8192 rows

    wt_prep<<<dim3(4, 4, 5), 256, 0, stream>>>(Wq, Wk, Wv, W1, W2, WT5);
    qkv_mfma<<<dim3(M / 16, 3), 256, 0, stream>>>(Q, K, WT5, bq, bk, bv, Qp, Kp, Vp);
    vt_prep<<<dim3(128, 4), 256, 0, stream>>>(Vp, VT);
    attn_mfma<<<BB * HH * (NN / 32), 256, 0, stream>>>(Qp, Kp, VT, Opre);
    ln_rows<<<M, 64, 0, stream>>>(Opre, g0, beta0, O);
    ffn1_mfma<<<M / 16, 256, 0, stream>>>(O, WT1, b1, H1);
    gemm_ffn2_ln<<<M / 16, 512, 0, stream>>>(H1, WT2, b2, O, g1, beta1, out);
}

// Round 2
// 206.118 us; speedup vs baseline: 1.2687x; 1.2425x over previous
//
#include <hip/hip_runtime.h>

// MAB block, MFMA bf16, round 8: fix L2-channel serialization in attention.
// r7 post-mortem: VGPR=52 < 72-reg minimum live state proved the compiler
// collapsed the reg pipeline, but the real bound is the V read pattern:
// VT[d][2048] rows are 4KB apart = SAME L2 channel for all 16 lanes, and all
// bh/l15 offsets are 4KB-multiples -> entire V traffic through ~1-2 of 16
// channels/XCD (~540 GB/s) -> 118us projected ~= 125us measured.
// r8: re-tile K and V into per-(b,h) 4KB key-tiles so every fragment load is
// a contiguous 1KB wave access (all channels striped):
//   KT [bh][tile64][dhalf2][key32][d32]  (16B-chunk permutation of Kp)
//   VT2[bh][tile64][d64][key32]          (tile-wise transpose)
// Attention body addressing becomes base + {0,512,1024,1536}. Everything
// else (block structure, softmax, merge, GEMMs) unchanged.

typedef float fx4 __attribute__((ext_vector_type(4)));
typedef short short8 __attribute__((ext_vector_type(8)));
typedef short shortx4 __attribute__((ext_vector_type(4)));
typedef unsigned int uint2v __attribute__((ext_vector_type(2)));

#define BB  4
#define NN  2048
#define DD  256
#define HH  4
#define DHH 64

__device__ __forceinline__ float bf2f(unsigned short u) {
    union { unsigned int i; float f; } v; v.i = ((unsigned int)u) << 16; return v.f;
}
__device__ __forceinline__ unsigned short f2bf(float f) {
    union { float f; unsigned int i; } v; v.f = f;
    unsigned int r = v.i + 0x7FFF + ((v.i >> 16) & 1);   // RNE
    return (unsigned short)(r >> 16);
}
__device__ __forceinline__ unsigned int fbits(float f) {
    union { float f; unsigned int i; } v; v.f = f; return v.i;
}
__device__ __forceinline__ unsigned int packbf(float lo, float hi) {
    unsigned int a = fbits(lo), b = fbits(hi);
    a = (a + 0x7FFF + ((a >> 16) & 1)) >> 16;
    b = (b + 0x7FFF + ((b >> 16) & 1)) & 0xFFFF0000u;
    return a | b;
}

// ---------------------------------------------------------------------------
// Weight prep: WT[n][k] = bf16(W[k][n]) for the 5 weight matrices (256x256).
// ---------------------------------------------------------------------------
__global__ __launch_bounds__(256) void wt_prep(
        const float* __restrict__ w0, const float* __restrict__ w1,
        const float* __restrict__ w2, const float* __restrict__ w3,
        const float* __restrict__ w4, unsigned short* __restrict__ dst) {
    __shared__ unsigned short T[64 * 73];
    const int tid = threadIdx.x;
    const int z = blockIdx.z;
    const float* W = (z == 0) ? w0 : (z == 1) ? w1 : (z == 2) ? w2 : (z == 3) ? w3 : w4;
    unsigned short* WT = dst + z * 65536;
    const int nb = blockIdx.x * 64, kb = blockIdx.y * 64;
    {
        int kl = tid >> 2, c0 = (tid & 3) * 16;
        const float* src = W + (size_t)(kb + kl) * DD + nb + c0;
#pragma unroll
        for (int i = 0; i < 16; ++i) T[kl * 73 + c0 + i] = f2bf(src[i]);
    }
    __syncthreads();
    {
        int nl = tid >> 2, k0 = (tid & 3) * 16;
        short8 o0, o1;
#pragma unroll
        for (int i = 0; i < 8; ++i) {
            o0[i] = (short)T[(k0 + i) * 73 + nl];
            o1[i] = (short)T[(k0 + 8 + i) * 73 + nl];
        }
        short8* d = (short8*)(WT + (size_t)(nb + nl) * DD + kb + k0);
        d[0] = o0; d[1] = o1;
    }
}

// ---------------------------------------------------------------------------
// V tile-transpose: VT2[bh][tile][d64][key32] <- Vp[b*2048+key][h*64+d].
// grid(128,4): b = bx>>5, keyb = (bx&31)*64 (2 tiles), hb = by.
// ---------------------------------------------------------------------------
__global__ __launch_bounds__(256) void vt_prep(
        const unsigned short* __restrict__ Vp, unsigned short* __restrict__ VT2) {
    __shared__ unsigned short T[64 * 73];
    const int tid = threadIdx.x;
    const int hb = blockIdx.y;
    const int b = blockIdx.x >> 5;
    const int keyb = (blockIdx.x & 31) * 64;
    const int bh = b * HH + hb;
    {
        int kl = tid >> 2, c0 = (tid & 3) * 16;
        const short8* src = (const short8*)(Vp + (size_t)(b * NN + keyb + kl) * DD + hb * DHH + c0);
        short8 v0 = src[0], v1 = src[1];
#pragma unroll
        for (int i = 0; i < 8; ++i) {
            T[kl * 73 + c0 + i]     = (unsigned short)v0[i];
            T[kl * 73 + c0 + 8 + i] = (unsigned short)v1[i];
        }
    }
    __syncthreads();
    {
        int dl = tid >> 2, k0 = (tid & 3) * 16;          // d row, key chunk (16)
        short8 o0, o1;
#pragma unroll
        for (int i = 0; i < 8; ++i) {
            o0[i] = (short)T[(k0 + i) * 73 + dl];
            o1[i] = (short)T[(k0 + 8 + i) * 73 + dl];
        }
        const int gkey = keyb + k0;                       // multiple of 16
        const int tl = gkey >> 5;                         // tile index
        const int kin = gkey & 31;                        // 0 or 16
        short8* d = (short8*)(VT2 + ((size_t)(bh * 64 + tl) * 64 + dl) * 32 + kin);
        d[0] = o0; d[1] = o1;
    }
}

// ---------------------------------------------------------------------------
// K tile-permute: KT[bh][tile][dhalf][key32][d32] <- Kp[b*2048+key][h*64+d].
// Pure 16B-chunk permutation; grid 1024 = bh*64 + tile, 256 threads.
// ---------------------------------------------------------------------------
__global__ __launch_bounds__(256) void kt_prep(
        const unsigned short* __restrict__ Kp, unsigned short* __restrict__ KT) {
    const int bh = blockIdx.x >> 6;
    const int tl = blockIdx.x & 63;
    const int b = bh >> 2, h = bh & 3;
    const int tid = threadIdx.x;
    const int key = tid >> 3, p = tid & 7;
    short8 v = *(const short8*)(Kp + (size_t)(b * NN + tl * 32 + key) * DD + h * DHH + p * 8);
    unsigned short* dst = KT + (size_t)(bh * 64 + tl) * 2048
                        + (p >> 2) * 1024 + key * 32 + (p & 3) * 8;
    *(short8*)dst = v;
}

// ---------------------------------------------------------------------------
// 32-row GEMM body: C[r0..r0+32, c-half] = A @ W + bias. 4 waves, wave =
// 32 rows x 32 cols. W-frags hoisted. AIN: 0 fp32 A, 1 bf16 A.
// EP: 0 bias->bf16, 1 relu->bf16.
// ---------------------------------------------------------------------------
template<int AIN, int EP>
__device__ __forceinline__ void gemm32_body(
        const void* __restrict__ Ain, const unsigned short* __restrict__ WT,
        const float* __restrict__ bias, void* __restrict__ Cout, int bx) {
    __shared__ unsigned short As[32 * 264];
    const int tid = threadIdx.x;
    const int lane = tid & 63, w = tid >> 6;
    const int l15 = lane & 15, quad = lane >> 4;
    const int r0 = (bx >> 1) * 32;
    const int c0w = (bx & 1) * 128 + w * 32;
    short8 wf[8][2];
#pragma unroll
    for (int kc = 0; kc < 8; ++kc)
#pragma unroll
        for (int dt = 0; dt < 2; ++dt)
            wf[kc][dt] = *(const short8*)(WT + (size_t)(c0w + dt * 16 + l15) * DD + kc * 32 + 8 * quad);
    float bv[2];
#pragma unroll
    for (int dt = 0; dt < 2; ++dt) bv[dt] = bias[c0w + dt * 16 + l15];
    {   // stage A tile (32 x 256) as bf16; thread: 32 elems
        int row = tid >> 3, c0 = (tid & 7) * 32;
        short8 o[4];
        if (AIN == 0) {
            const fx4* s4 = (const fx4*)((const float*)Ain + (size_t)(r0 + row) * DD + c0);
#pragma unroll
            for (int j = 0; j < 4; ++j) {
                fx4 v0 = s4[2 * j], v1 = s4[2 * j + 1];
#pragma unroll
                for (int i = 0; i < 4; ++i) {
                    o[j][i]     = (short)f2bf(v0[i]);
                    o[j][i + 4] = (short)f2bf(v1[i]);
                }
            }
        } else {
            const short8* s8 = (const short8*)((const unsigned short*)Ain + (size_t)(r0 + row) * DD + c0);
#pragma unroll
            for (int j = 0; j < 4; ++j) o[j] = s8[j];
        }
        short8* d = (short8*)(As + row * 264 + c0);
#pragma unroll
        for (int j = 0; j < 4; ++j) d[j] = o[j];
    }
    __syncthreads();
    fx4 acc[2][2];
#pragma unroll
    for (int mt = 0; mt < 2; ++mt)
#pragma unroll
        for (int dt = 0; dt < 2; ++dt) acc[mt][dt] = (fx4){0.f, 0.f, 0.f, 0.f};
#pragma unroll
    for (int kc = 0; kc < 8; ++kc) {
        short8 a0 = *(const short8*)(As + l15 * 264 + kc * 32 + 8 * quad);
        short8 a1 = *(const short8*)(As + (16 + l15) * 264 + kc * 32 + 8 * quad);
#pragma unroll
        for (int dt = 0; dt < 2; ++dt) {
            acc[0][dt] = __builtin_amdgcn_mfma_f32_16x16x32_bf16(a0, wf[kc][dt], acc[0][dt], 0, 0, 0);
            acc[1][dt] = __builtin_amdgcn_mfma_f32_16x16x32_bf16(a1, wf[kc][dt], acc[1][dt], 0, 0, 0);
        }
    }
#pragma unroll
    for (int mt = 0; mt < 2; ++mt)
#pragma unroll
        for (int r = 0; r < 4; ++r) {
            const size_t grow = r0 + mt * 16 + 4 * quad + r;
#pragma unroll
            for (int dt = 0; dt < 2; ++dt) {
                float v = acc[mt][dt][r] + bv[dt];
                if (EP == 1) v = fmaxf(v, 0.0f);
                ((unsigned short*)Cout)[grow * DD + c0w + dt * 16 + l15] = f2bf(v);
            }
        }
}

// Fused QKV projections: grid (512, 3); y selects {Q->Qp, K->Kp, K->Vp}.
__global__ __launch_bounds__(256, 4) void qkv_mfma(
        const float* __restrict__ Q, const float* __restrict__ K,
        const unsigned short* __restrict__ WT5,
        const float* __restrict__ bq, const float* __restrict__ bk,
        const float* __restrict__ bv,
        unsigned short* __restrict__ Qp, unsigned short* __restrict__ Kp,
        unsigned short* __restrict__ Vp) {
    const int z = blockIdx.y;
    const float* A = (z == 0) ? Q : K;
    const float* bias = (z == 0) ? bq : (z == 1) ? bk : bv;
    unsigned short* C = (z == 0) ? Qp : (z == 1) ? Kp : Vp;
    gemm32_body<0, 0>(A, WT5 + z * 65536, bias, C, blockIdx.x);
}

// FFN1: H1 = relu(O @ W1 + b1), O fp32.
__global__ __launch_bounds__(256, 4) void ffn1_mfma(
        const float* __restrict__ O, const unsigned short* __restrict__ WT1,
        const float* __restrict__ b1, unsigned short* __restrict__ H1) {
    gemm32_body<0, 1>(O, WT1, b1, H1, blockIdx.x);
}

// ---------------------------------------------------------------------------
// FFN2 + residual + LayerNorm fused: out = LN(R + A@W2 + b2), fp32 out.
// Block = 16 rows x 256 cols, 8 waves (wave = 16x32), W-frags hoisted.
// ---------------------------------------------------------------------------
__global__ __launch_bounds__(512, 4) void gemm_ffn2_ln(
        const unsigned short* __restrict__ Ain, const unsigned short* __restrict__ WT,
        const float* __restrict__ bias, const float* __restrict__ R,
        const float* __restrict__ g, const float* __restrict__ be,
        float* __restrict__ out) {
    __shared__ unsigned short As[16 * 264];
    __shared__ float lnb[2][8][16];
    const int tid = threadIdx.x;
    const int lane = tid & 63, w = tid >> 6;          // w in 0..7
    const int l15 = lane & 15, quad = lane >> 4;
    const int r0 = blockIdx.x * 16;
    const int c0w = w * 32;
    short8 wf[8][2];
#pragma unroll
    for (int kc = 0; kc < 8; ++kc)
#pragma unroll
        for (int dt = 0; dt < 2; ++dt)
            wf[kc][dt] = *(const short8*)(WT + (size_t)(c0w + dt * 16 + l15) * DD + kc * 32 + 8 * quad);
    float bv[2], gv[2], ev[2];
#pragma unroll
    for (int dt = 0; dt < 2; ++dt) {
        int col = c0w + dt * 16 + l15;
        bv[dt] = bias[col]; gv[dt] = g[col]; ev[dt] = be[col];
    }
    {   // stage A: 512 threads x 16B
        int row = tid >> 5, c0 = (tid & 31) * 8;
        *(short8*)(As + row * 264 + c0) = *(const short8*)(Ain + (size_t)(r0 + row) * DD + c0);
    }
    __syncthreads();
    fx4 acc[2];
#pragma unroll
    for (int i = 0; i < 2; ++i) acc[i] = (fx4){0.f, 0.f, 0.f, 0.f};
#pragma unroll
    for (int kc = 0; kc < 8; ++kc) {
        short8 a = *(const short8*)(As + l15 * 264 + kc * 32 + 8 * quad);
#pragma unroll
        for (int dt = 0; dt < 2; ++dt)
            acc[dt] = __builtin_amdgcn_mfma_f32_16x16x32_bf16(a, wf[kc][dt], acc[dt], 0, 0, 0);
    }
    float v[4][2], p1[4], p2[4];
#pragma unroll
    for (int r = 0; r < 4; ++r) {
        p1[r] = 0.f; p2[r] = 0.f;
        const size_t grow = r0 + 4 * quad + r;
#pragma unroll
        for (int dt = 0; dt < 2; ++dt) {
            float x = acc[dt][r] + bv[dt] + R[grow * DD + c0w + dt * 16 + l15];
            v[r][dt] = x; p1[r] += x; p2[r] += x * x;
        }
    }
#pragma unroll
    for (int r = 0; r < 4; ++r) {
#pragma unroll
        for (int off = 1; off <= 8; off <<= 1) {
            p1[r] += __shfl_xor(p1[r], off);
            p2[r] += __shfl_xor(p2[r], off);
        }
    }
    if (l15 == 0) {
#pragma unroll
        for (int r = 0; r < 4; ++r) {
            lnb[0][w][4 * quad + r] = p1[r];
            lnb[1][w][4 * quad + r] = p2[r];
        }
    }
    __syncthreads();
#pragma unroll
    for (int r = 0; r < 4; ++r) {
        const int row = 4 * quad + r;
        float s1 = 0.f, s2 = 0.f;
#pragma unroll
        for (int ww = 0; ww < 8; ++ww) { s1 += lnb[0][ww][row]; s2 += lnb[1][ww][row]; }
        float mean = s1 * (1.0f / 256.0f);
        float var  = s2 * (1.0f / 256.0f) - mean * mean;
        float rstd = rsqrtf(var + 1e-5f);
        const size_t grow = r0 + row;
#pragma unroll
        for (int dt = 0; dt < 2; ++dt)
            out[grow * DD + c0w + dt * 16 + l15] = (v[r][dt] - mean) * rstd * gv[dt] + ev[dt];
    }
}

// ---------------------------------------------------------------------------
// Flash attention, O^T form, no-max softmax (|s| <= ~2 by construction).
// Block = 32 q-rows, 4 waves: wave w -> q-subtile (w&1), K-half (w>>1).
// Per 32-key tile: S^T = K.Q^T (C col = q = l15) -> p = exp(s/8) per-thread
// -> pack -> XOR-swizzled LDS exchange -> od^T += V^T.P^T (od col = q).
// r8: K/V fragments come from the 4KB-tiled KT/VT2 layouts -> every fragment
// load is a contiguous 1KB wave access (L2 channels striped); per-body
// addressing is base + {0,512,1024,1536}.
// ---------------------------------------------------------------------------
__global__ __launch_bounds__(256, 4) void attn_mfma(
        const unsigned short* __restrict__ Qp, const unsigned short* __restrict__ KT,
        const unsigned short* __restrict__ VT2, float* __restrict__ Opre) {
    __shared__ unsigned int pbuf[4][256];     // per-wave P exchange, pitch 16 dw
    __shared__ float macc[2][16][68];         // kh0 partial O^T [qs][q][d]
    __shared__ float lbuf[32];                // kh0 partial l    [qs*16+q]
    const int tid = threadIdx.x;
    const int lane = tid & 63, w = tid >> 6;
    const int l15 = lane & 15, quad = lane >> 4;
    const int qs = w & 1, kh = w >> 1;
    const int gb = blockIdx.x;
    const int bh = ((gb & 7) << 1) | ((gb >> 9) & 1);   // XCD-locality swizzle
    const int qc = (gb >> 3) & 63;
    const int h  = bh & 3;
    const int b  = bh >> 2;
    const int qrow = qc * 32 + qs * 16;
    const int sw = 4 * ((l15 >> 1) & 3);                // bank swizzle (per l15)

    short8 aq0, aq1;
    {
        const unsigned short* qptr = Qp + ((size_t)(b * NN + qrow + l15) * DD + h * DHH + 8 * quad);
        aq0 = *(const short8*)qptr;
        aq1 = *(const short8*)(qptr + 32);
    }
    fx4 od0 = (fx4){0.f, 0.f, 0.f, 0.f};
    fx4 od1 = (fx4){0.f, 0.f, 0.f, 0.f};
    fx4 od2 = (fx4){0.f, 0.f, 0.f, 0.f};
    fx4 od3 = (fx4){0.f, 0.f, 0.f, 0.f};
    float lsum = 0.0f;

    unsigned int* pw = &pbuf[w][0];
    const int wcol = (2 * quad) ^ sw;         // write cols (pairs t=2q,2q+1 / +8)
    const int rcol = (4 * quad) ^ sw;         // read col group (t=4Q..4Q+3)
    // per-(bh, kh-half) tile bases, including per-lane offset l15*32 + 8*quad
    const unsigned short* kthead = KT  + ((size_t)(bh * 64) + kh * 32) * 2048 + l15 * 32 + 8 * quad;
    const unsigned short* vthead = VT2 + ((size_t)(bh * 64) + kh * 32) * 2048 + l15 * 32 + 8 * quad;

    // loop state: named registers only
    short8 ka0, ka1, ka2, ka3;     // K frags, buffer A
    short8 kb0, kb1, kb2, kb3;     // K frags, buffer B
    short8 v0, v1, v2, v3;         // V frags, current tile

#define PREF_K(K0, K1, K2, K3, T) do {                                        \
        const unsigned short* kb_ = kthead + (size_t)(T) * 2048;              \
        K0 = *(const short8*)(kb_);          /* keys l15,    d 8q..8q+7  */   \
        K1 = *(const short8*)(kb_ + 1024);   /* keys l15,    d 32+8q..   */   \
        K2 = *(const short8*)(kb_ + 512);    /* keys 16+l15, d 8q..      */   \
        K3 = *(const short8*)(kb_ + 1536);   /* keys 16+l15, d 32+8q..   */   \
    } while (0)

#define PREF_V(T) do {                                                        \
        const unsigned short* vb_ = vthead + (size_t)(T) * 2048;              \
        v0 = *(const short8*)(vb_);          /* d l15,    keys 8q..8q+7 */    \
        v1 = *(const short8*)(vb_ + 512);    /* d 16+l15                */    \
        v2 = *(const short8*)(vb_ + 1024);   /* d 32+l15                */    \
        v3 = *(const short8*)(vb_ + 1536);   /* d 48+l15                */    \
    } while (0)

#define BODY(CK0, CK1, CK2, CK3, NK0, NK1, NK2, NK3, T) do {                  \
        PREF_V(T);                            /* V for THIS tile (used last) */\
        const int tn_ = ((T) + 1 < 32) ? (T) + 1 : 31;                        \
        PREF_K(NK0, NK1, NK2, NK3, tn_);      /* K for NEXT tile */           \
        const fx4 z_ = (fx4){0.f, 0.f, 0.f, 0.f};                             \
        fx4 s0_ = __builtin_amdgcn_mfma_f32_16x16x32_bf16(CK0, aq0, z_, 0, 0, 0); \
        s0_     = __builtin_amdgcn_mfma_f32_16x16x32_bf16(CK1, aq1, s0_, 0, 0, 0); \
        fx4 s1_ = __builtin_amdgcn_mfma_f32_16x16x32_bf16(CK2, aq0, z_, 0, 0, 0); \
        s1_     = __builtin_amdgcn_mfma_f32_16x16x32_bf16(CK3, aq1, s1_, 0, 0, 0); \
        s0_[0] = __expf(s0_[0] * 0.125f); s0_[1] = __expf(s0_[1] * 0.125f);   \
        s0_[2] = __expf(s0_[2] * 0.125f); s0_[3] = __expf(s0_[3] * 0.125f);   \
        s1_[0] = __expf(s1_[0] * 0.125f); s1_[1] = __expf(s1_[1] * 0.125f);   \
        s1_[2] = __expf(s1_[2] * 0.125f); s1_[3] = __expf(s1_[3] * 0.125f);   \
        lsum += s0_[0] + s0_[1] + s0_[2] + s0_[3];                            \
        lsum += s1_[0] + s1_[1] + s1_[2] + s1_[3];                            \
        uint2v w1_ = (uint2v){packbf(s0_[0], s0_[1]), packbf(s0_[2], s0_[3])};\
        uint2v w2_ = (uint2v){packbf(s1_[0], s1_[1]), packbf(s1_[2], s1_[3])};\
        *(uint2v*)(pw + l15 * 16 + wcol)       = w1_;   /* pairs t=2q,2q+1 */ \
        *(uint2v*)(pw + l15 * 16 + (wcol ^ 8)) = w2_;   /* pairs t=8+2q..  */ \
        short8 bp_ = *(const short8*)(pw + l15 * 16 + rcol); /* keys 8q..+7 */\
        od0 = __builtin_amdgcn_mfma_f32_16x16x32_bf16(v0, bp_, od0, 0, 0, 0); \
        od1 = __builtin_amdgcn_mfma_f32_16x16x32_bf16(v1, bp_, od1, 0, 0, 0); \
        od2 = __builtin_amdgcn_mfma_f32_16x16x32_bf16(v2, bp_, od2, 0, 0, 0); \
        od3 = __builtin_amdgcn_mfma_f32_16x16x32_bf16(v3, bp_, od3, 0, 0, 0); \
    } while (0)

    PREF_K(ka0, ka1, ka2, ka3, 0);
    for (int tt = 0; tt < 16; ++tt) {
        BODY(ka0, ka1, ka2, ka3, kb0, kb1, kb2, kb3, 2 * tt);
        BODY(kb0, kb1, kb2, kb3, ka0, ka1, ka2, ka3, 2 * tt + 1);
    }
#undef BODY
#undef PREF_V
#undef PREF_K

    // per-q total l for this wave (sum over quads)
    lsum += __shfl_xor(lsum, 16);
    lsum += __shfl_xor(lsum, 32);
    // ---- merge the two K-halves (plain adds; no max state) ----
    if (kh == 0) {
        *(fx4*)&macc[qs][l15][0 * 16 + 4 * quad] = od0;
        *(fx4*)&macc[qs][l15][1 * 16 + 4 * quad] = od1;
        *(fx4*)&macc[qs][l15][2 * 16 + 4 * quad] = od2;
        *(fx4*)&macc[qs][l15][3 * 16 + 4 * quad] = od3;
        if (quad == 0) lbuf[qs * 16 + l15] = lsum;
    }
    __syncthreads();
    if (kh == 1) {
        const float inv = 1.0f / (lsum + lbuf[qs * 16 + l15]);
        const size_t grow = (size_t)(b * NN) + qrow + l15;
        float* obase = Opre + grow * DD + h * DHH;
        const unsigned short* qpb = Qp + grow * DD + h * DHH;
#define OUT_DT(DT, OD) do {                                                   \
        fx4 mv_ = *(const fx4*)&macc[qs][l15][(DT) * 16 + 4 * quad];          \
        shortx4 rv_ = *(const shortx4*)(qpb + (DT) * 16 + 4 * quad);          \
        fx4 o_;                                                               \
        o_[0] = (OD[0] + mv_[0]) * inv + bf2f((unsigned short)rv_[0]);        \
        o_[1] = (OD[1] + mv_[1]) * inv + bf2f((unsigned short)rv_[1]);        \
        o_[2] = (OD[2] + mv_[2]) * inv + bf2f((unsigned short)rv_[2]);        \
        o_[3] = (OD[3] + mv_[3]) * inv + bf2f((unsigned short)rv_[3]);        \
        *(fx4*)(obase + (DT) * 16 + 4 * quad) = o_;                           \
    } while (0)
        OUT_DT(0, od0);
        OUT_DT(1, od1);
        OUT_DT(2, od2);
        OUT_DT(3, od3);
#undef OUT_DT
    }
}

// row LayerNorm: Y = LN(X)*g+be (fp32)
__global__ __launch_bounds__(64) void ln_rows(
        const float* __restrict__ X, const float* __restrict__ g,
        const float* __restrict__ be, float* __restrict__ Y) {
    const int lane = threadIdx.x;
    const size_t row = blockIdx.x;
    fx4 v = ((const fx4*)(X + row * DD))[lane];
    float s1 = v[0]+v[1]+v[2]+v[3];
    float s2 = v[0]*v[0]+v[1]*v[1]+v[2]*v[2]+v[3]*v[3];
#pragma unroll
    for (int off = 32; off >= 1; off >>= 1) {
        s1 += __shfl_xor(s1, off); s2 += __shfl_xor(s2, off);
    }
    float mean = s1 * (1.0f/256.0f);
    float var  = s2 * (1.0f/256.0f) - mean * mean;
    float rstd = rsqrtf(var + 1e-5f);
    fx4 gv = ((const fx4*)g)[lane];
    fx4 ev = ((const fx4*)be)[lane];
    fx4 o;
#pragma unroll
    for (int i = 0; i < 4; ++i) o[i] = (v[i]-mean)*rstd*gv[i] + ev[i];
    ((fx4*)(Y + row * DD))[lane] = o;
}

extern "C" void kernel_launch(void* const* d_in, const int* in_sizes, int n_in,
                              void* d_out, int out_size, void* d_ws, size_t ws_size,
                              hipStream_t stream) {
    (void)in_sizes; (void)n_in; (void)out_size; (void)ws_size;
    const float* Q     = (const float*)d_in[0];
    const float* K     = (const float*)d_in[1];
    const float* Wq    = (const float*)d_in[2];
    const float* bq    = (const float*)d_in[3];
    const float* Wk    = (const float*)d_in[4];
    const float* bk    = (const float*)d_in[5];
    const float* Wv    = (const float*)d_in[6];
    const float* bv    = (const float*)d_in[7];
    const float* W1    = (const float*)d_in[8];
    const float* b1    = (const float*)d_in[9];
    const float* W2    = (const float*)d_in[10];
    const float* b2    = (const float*)d_in[11];
    const float* g0    = (const float*)d_in[12];
    const float* beta0 = (const float*)d_in[13];
    const float* g1    = (const float*)d_in[14];
    const float* beta1 = (const float*)d_in[15];

    // Workspace: [0,4)Mi Qp bf16 (later H1 bf16); [4,8)Mi Kp; [8,12)Mi Vp
    // (reused as KT after vt_prep); [12,16)Mi VT2; [16,24)Mi Opre f32;
    // [24,32)Mi O f32; [32Mi,+640K) WT x5
    char* ws = (char*)d_ws;
    unsigned short* Qp  = (unsigned short*)(ws);
    unsigned short* Kp  = (unsigned short*)(ws + (4u  << 20));
    unsigned short* Vp  = (unsigned short*)(ws + (8u  << 20));
    unsigned short* KT  = Vp;                       // overlays Vp (dead after vt_prep)
    unsigned short* VT2 = (unsigned short*)(ws + (12u << 20));
    float*          Opre= (float*)(ws + (16u << 20));
    float*          O   = (float*)(ws + (24u << 20));
    unsigned short* WT5 = (unsigned short*)(ws + (32u << 20));
    unsigned short* H1  = Qp;
    float*          out = (float*)d_out;

    const unsigned short* WT1 = WT5 + 3 * 65536;
    const unsigned short* WT2 = WT5 + 4 * 65536;

    const int M = BB * NN;                        // 8192 rows

    wt_prep<<<dim3(4, 4, 5), 256, 0, stream>>>(Wq, Wk, Wv, W1, W2, WT5);
    qkv_mfma<<<dim3(M / 16, 3), 256, 0, stream>>>(Q, K, WT5, bq, bk, bv, Qp, Kp, Vp);
    vt_prep<<<dim3(128, 4), 256, 0, stream>>>(Vp, VT2);
    kt_prep<<<1024, 256, 0, stream>>>(Kp, KT);    // overwrites Vp slot (Vp dead)
    attn_mfma<<<BB * HH * (NN / 32), 256, 0, stream>>>(Qp, KT, VT2, Opre);
    ln_rows<<<M, 64, 0, stream>>>(Opre, g0, beta0, O);
    ffn1_mfma<<<M / 16, 256, 0, stream>>>(O, WT1, b1, H1);
    gemm_ffn2_ln<<<M / 16, 512, 0, stream>>>(H1, WT2, b2, O, g1, beta1, out);
}